// Round 2
// baseline (1369.067 us; speedup 1.0000x reference)
//
#include <hip/hip_runtime.h>
#include <math.h>

#define NN 8192
#define EE 131072
#define CC 64
#define GG 32

__device__ __forceinline__ float silu_f(float x) { return x / (1.0f + __expf(-x)); }

// ---------------- h0 = node_attrs @ W_embed ; elem = argmax(node_attrs) -------------
__global__ __launch_bounds__(256) void k_h0(const float* __restrict__ na,
                                            const float* __restrict__ Wemb,
                                            float* __restrict__ h0,
                                            int* __restrict__ elem) {
    int n = blockIdx.x * 4 + (threadIdx.x >> 6);
    int d = threadIdx.x & 63;
    float acc = 0.0f;
    float best = -1.0f; int bi = 0;
    #pragma unroll
    for (int k = 0; k < 10; k++) {
        float a = na[n * 10 + k];
        acc += a * Wemb[k * 64 + d];
        if (a > best) { best = a; bi = k; }
    }
    h0[n * 64 + d] = acc;
    if (d == 0) elem[n] = bi;
}

// ---------------- tiled edge kernel: 64 edges per block ----------------------------
// Computes radial MLP (8 -> 64 -> 128) for a tile of 64 edges with register-tiled
// LDS GEMM, then atomically scatters messages into A[n,4,64].
__global__ __launch_bounds__(256) void edge_tile(
    const float* __restrict__ feats,  // (N,C)
    const float* __restrict__ pos,    // (N,3)
    const float* __restrict__ shifts, // (E,3)
    const int*   __restrict__ eidx,   // (2,E)
    const float* __restrict__ Wra,    // (8,64)
    const float* __restrict__ Wrb,    // (64,256) cols 0..127 used
    float* __restrict__ A)            // (N,4,C)
{
    __shared__ float sWaT[64 * 8];     // [j][b]
    __shared__ float sWbT[128 * 64];   // [c][j] j-blocks XOR-swizzled, scaled
    __shared__ float sRb[8 * 64];      // [b][e]
    __shared__ float sHidT[64 * 68];   // [e][j], row stride 68 floats
    __shared__ float sFeat[64 * 68];   // [e][c], row stride 68 floats
    __shared__ float sU[3 * 64];
    __shared__ int   sSnd[64];
    __shared__ int   sRcv[64];
    __shared__ int   sLive[64];

    int tid = threadIdx.x;
    int e_base = blockIdx.x * 64;

    // ---- phase A: geometry + radial basis (threads 0..63) + weight staging (all) --
    if (tid < 64) {
        int e = e_base + tid;
        int snd = eidx[e];
        int rcv = eidx[EE + e];
        float vx = pos[rcv * 3 + 0] - pos[snd * 3 + 0] + shifts[e * 3 + 0];
        float vy = pos[rcv * 3 + 1] - pos[snd * 3 + 1] + shifts[e * 3 + 1];
        float vz = pos[rcv * 3 + 2] - pos[snd * 3 + 2] + shifts[e * 3 + 2];
        float r = sqrtf(vx * vx + vy * vy + vz * vz + 1e-12f);
        float rinv = 1.0f / r;
        float x = r * 0.2f;
        int live = x < 1.0f;
        float pref = 0.0f;
        if (live) {
            float x2 = x * x, x4 = x2 * x2, x5 = x4 * x;
            float env = 1.0f - 21.0f * x5 + 35.0f * x5 * x - 15.0f * x5 * x2;
            pref = 0.632455532033676f * rinv * env;
        }
        float s1, c1;
        __sincosf(0.62831853071795865f * r, &s1, &c1);   // theta = pi/5 * r
        float k2c = 2.0f * c1;
        float sp = 0.0f, sn = s1;
        #pragma unroll
        for (int b = 0; b < 8; b++) {
            sRb[b * 64 + tid] = pref * sn;
            float t = k2c * sn - sp; sp = sn; sn = t;
        }
        sU[tid]       = vx * rinv;
        sU[64 + tid]  = vy * rinv;
        sU[128 + tid] = vz * rinv;
        sSnd[tid] = snd; sRcv[tid] = rcv; sLive[tid] = live;
    }
    // stage Wa transposed: sWaT[j][b]
    for (int idx = tid; idx < 512; idx += 256) {
        int b = idx >> 6, j = idx & 63;
        sWaT[j * 8 + b] = Wra[idx];
    }
    // stage Wb transposed [c][j], j-block XOR swizzle, scale folded (1/16, sqrt3/16)
    for (int idx = tid; idx < 64 * 128; idx += 256) {
        int j = idx >> 7, c = idx & 127;
        float v = Wrb[j * 256 + c] * (c < 64 ? 0.0625f : 0.10825317547305482f);
        int jb = j >> 2, jl = j & 3;
        int sj = ((jb ^ ((c >> 3) & 7)) << 2) | jl;
        sWbT[c * 64 + sj] = v;
    }
    __syncthreads();

    // ---- phase B: hidden layer (all 256 threads) + feats staging ------------------
    {
        int e = tid & 63, jg = tid >> 6;
        float rbv[8];
        #pragma unroll
        for (int b = 0; b < 8; b++) rbv[b] = sRb[b * 64 + e];
        const float4* waT4 = (const float4*)sWaT;
        float hid[16];
        #pragma unroll
        for (int jj = 0; jj < 16; jj++) {
            int j = jg * 16 + jj;
            float4 wa0 = waT4[j * 2 + 0];
            float4 wa1 = waT4[j * 2 + 1];
            float acc = rbv[0] * wa0.x + rbv[1] * wa0.y + rbv[2] * wa0.z + rbv[3] * wa0.w
                      + rbv[4] * wa1.x + rbv[5] * wa1.y + rbv[6] * wa1.z + rbv[7] * wa1.w;
            hid[jj] = silu_f(acc);
        }
        float4* hidT4 = (float4*)sHidT;
        #pragma unroll
        for (int q = 0; q < 4; q++) {
            hidT4[e * 17 + jg * 4 + q] =
                make_float4(hid[q * 4 + 0], hid[q * 4 + 1], hid[q * 4 + 2], hid[q * 4 + 3]);
        }
    }
    {
        // stage feats rows for tile edges: thread -> (e = tid>>2, part = tid&3)
        int e = tid >> 2, part = tid & 3;
        const float4* src = (const float4*)(feats + (size_t)sSnd[e] * CC);
        float4* dst4 = (float4*)(sFeat + e * 68);
        #pragma unroll
        for (int q = 0; q < 4; q++) dst4[part * 4 + q] = src[part * 4 + q];
    }
    __syncthreads();

    // ---- phase C: wrf = hid @ WbT, register tile 4e x 8c --------------------------
    int cg = tid & 15, eg = tid >> 4;
    int e0 = eg * 4, c0 = cg * 8, cgl = cg & 7;
    const float4* hidT4 = (const float4*)sHidT;  // row stride 17
    const float4* wbT4  = (const float4*)sWbT;   // row stride 16
    float acc[4][8];
    #pragma unroll
    for (int i = 0; i < 4; i++)
        #pragma unroll
        for (int cc = 0; cc < 8; cc++) acc[i][cc] = 0.0f;

    for (int jb = 0; jb < 16; ++jb) {
        float4 h0_ = hidT4[(e0 + 0) * 17 + jb];
        float4 h1_ = hidT4[(e0 + 1) * 17 + jb];
        float4 h2_ = hidT4[(e0 + 2) * 17 + jb];
        float4 h3_ = hidT4[(e0 + 3) * 17 + jb];
        int wj = jb ^ cgl;
        #pragma unroll
        for (int cc = 0; cc < 8; cc++) {
            float4 wb = wbT4[(c0 + cc) * 16 + wj];
            acc[0][cc] += h0_.x * wb.x + h0_.y * wb.y + h0_.z * wb.z + h0_.w * wb.w;
            acc[1][cc] += h1_.x * wb.x + h1_.y * wb.y + h1_.z * wb.z + h1_.w * wb.w;
            acc[2][cc] += h2_.x * wb.x + h2_.y * wb.y + h2_.z * wb.z + h2_.w * wb.w;
            acc[3][cc] += h3_.x * wb.x + h3_.y * wb.y + h3_.z * wb.z + h3_.w * wb.w;
        }
    }

    // ---- scatter: atomics into A (skip dead edges) --------------------------------
    if (cg < 8) {
        int c0l = cg * 8;
        #pragma unroll
        for (int i = 0; i < 4; i++) {
            int e = e0 + i;
            if (!sLive[e]) continue;
            float* Ar = A + (size_t)sRcv[e] * 256 + c0l;
            const float* fb = sFeat + e * 68 + c0l;
            #pragma unroll
            for (int cc = 0; cc < 8; cc++) atomicAdd(Ar + cc, acc[i][cc] * fb[cc]);
        }
    } else {
        int c1 = (cg - 8) * 8;
        #pragma unroll
        for (int i = 0; i < 4; i++) {
            int e = e0 + i;
            if (!sLive[e]) continue;
            float ux = sU[e], uy = sU[64 + e], uz = sU[128 + e];
            float* Ar = A + (size_t)sRcv[e] * 256;
            const float* fb = sFeat + e * 68 + c1;
            #pragma unroll
            for (int cc = 0; cc < 8; cc++) {
                float g = acc[i][cc] * fb[cc];
                atomicAdd(Ar + 64 + c1 + cc,  g * ux);
                atomicAdd(Ar + 128 + c1 + cc, g * uy);
                atomicAdd(Ar + 192 + c1 + cc, g * uz);
            }
        }
    }
}

// ---------------- node update 1 (4 nodes per block) --------------------------------
__global__ __launch_bounds__(256) void node1(
    const float* __restrict__ h0, const int* __restrict__ elem,
    const float* __restrict__ A,
    const float* __restrict__ Wmix1, const float* __restrict__ Wsc1,
    const float* __restrict__ Wp1s, const float* __restrict__ Wp1v,
    const float* __restrict__ Wp10, const float* __restrict__ Wp11,
    const float* __restrict__ wrd1,
    float* __restrict__ out0, float* __restrict__ out1, float* __restrict__ d1)
{
    int grp = threadIdx.x >> 6, d = threadIdx.x & 63;
    int n = blockIdx.x * 4 + grp;
    __shared__ float sA[4][256];
    __shared__ float sh0[4][64];
    __shared__ float sm0[4][64];
    __shared__ float st[4][3 * 64];

    #pragma unroll
    for (int k = 0; k < 4; k++) sA[grp][k * 64 + d] = A[(size_t)n * 256 + k * 64 + d];
    sh0[grp][d] = h0[n * 64 + d];
    __syncthreads();

    int en = elem[n];
    float h1v[4];
    #pragma unroll
    for (int k = 0; k < 4; k++) {
        const float* Wm = Wmix1 + (k ? 4096 : 0);
        const float4* a4 = (const float4*)&sA[grp][k * 64];
        float acc = 0.0f;
        for (int c4 = 0; c4 < 16; c4++) {
            float4 a = a4[c4]; int cb = c4 * 4;
            acc += a.x * Wm[cb * 64 + d] + a.y * Wm[(cb + 1) * 64 + d]
                 + a.z * Wm[(cb + 2) * 64 + d] + a.w * Wm[(cb + 3) * 64 + d];
        }
        h1v[k] = acc;
    }
    const float* Ws = Wsc1 + en * 4096;
    float sc = 0.0f;
    {
        const float4* a4 = (const float4*)&sh0[grp][0];
        for (int c4 = 0; c4 < 16; c4++) {
            float4 a = a4[c4]; int cb = c4 * 4;
            sc += a.x * Ws[cb * 64 + d] + a.y * Ws[(cb + 1) * 64 + d]
                + a.z * Ws[(cb + 2) * 64 + d] + a.w * Ws[(cb + 3) * 64 + d];
        }
    }

    float s = h1v[0];
    float ws0 = Wp1s[en * 64 + d], ws1 = Wp1s[640 + en * 64 + d], ws2 = Wp1s[1280 + en * 64 + d];
    float wv0 = Wp1v[en * 64 + d], wv1 = Wp1v[640 + en * 64 + d], wv2 = Wp1v[1280 + en * 64 + d];
    float m0 = ws0 * s + ws1 * s * s + ws2 * s * s * s;
    float gv = wv0 + wv1 * s + wv2 * s * s;
    sm0[grp][d] = m0;
    st[grp][0 * 64 + d] = h1v[1] * gv;
    st[grp][1 * 64 + d] = h1v[2] * gv;
    st[grp][2 * 64 + d] = h1v[3] * gv;
    __syncthreads();

    float o0 = sc;
    {
        const float4* a4 = (const float4*)&sm0[grp][0];
        for (int c4 = 0; c4 < 16; c4++) {
            float4 a = a4[c4]; int cb = c4 * 4;
            o0 += a.x * Wp10[cb * 64 + d] + a.y * Wp10[(cb + 1) * 64 + d]
                + a.z * Wp10[(cb + 2) * 64 + d] + a.w * Wp10[(cb + 3) * 64 + d];
        }
    }
    out0[n * 64 + d] = o0;

    float wr = wrd1[d];
    #pragma unroll
    for (int m = 0; m < 3; m++) {
        const float4* a4 = (const float4*)&st[grp][m * 64];
        float acc = 0.0f;
        for (int c4 = 0; c4 < 16; c4++) {
            float4 a = a4[c4]; int cb = c4 * 4;
            acc += a.x * Wp11[cb * 64 + d] + a.y * Wp11[(cb + 1) * 64 + d]
                 + a.z * Wp11[(cb + 2) * 64 + d] + a.w * Wp11[(cb + 3) * 64 + d];
        }
        out1[((size_t)n * 3 + m) * 64 + d] = acc;
        float v = acc * wr;
        #pragma unroll
        for (int off = 32; off > 0; off >>= 1) v += __shfl_down(v, off);
        if (d == 0) d1[n * 3 + m] = v;
    }
}

// ---------------- node update 2 + readout (4 nodes per block) ----------------------
__global__ __launch_bounds__(256) void node2(
    const int* __restrict__ elem, const float* __restrict__ A,
    const float* __restrict__ out1, const float* __restrict__ d1,
    const float* __restrict__ Wmix2, const float* __restrict__ Wsc2,
    const float* __restrict__ Wpr2, const float* __restrict__ Wp2,
    const float* __restrict__ Wv, const float* __restrict__ Wg1,
    const float* __restrict__ bg1, const float* __restrict__ Wg2,
    const float* __restrict__ bg2, const float* __restrict__ wrd2,
    const int* __restrict__ batch, const float* __restrict__ chg,
    const float* __restrict__ pos,
    float* __restrict__ total, float* __restrict__ dip)
{
    int grp = threadIdx.x >> 6, d = threadIdx.x & 63;
    int n = blockIdx.x * 4 + grp;
    __shared__ float sA[4][256];
    __shared__ float so1[4][3 * 64];
    __shared__ float st[4][3 * 64];
    __shared__ float so2[4][3 * 64];
    __shared__ float svh[4][48];
    __shared__ float sv[4][16];
    __shared__ float s_silu[4][16];
    __shared__ float s_aw[4][16];

    #pragma unroll
    for (int k = 0; k < 4; k++) sA[grp][k * 64 + d] = A[(size_t)n * 256 + k * 64 + d];
    #pragma unroll
    for (int m = 0; m < 3; m++) so1[grp][m * 64 + d] = out1[((size_t)n * 3 + m) * 64 + d];
    __syncthreads();

    int en = elem[n];
    float h2v[4];
    #pragma unroll
    for (int k = 0; k < 4; k++) {
        const float* Wm = Wmix2 + (k ? 4096 : 0);
        const float4* a4 = (const float4*)&sA[grp][k * 64];
        float acc = 0.0f;
        for (int c4 = 0; c4 < 16; c4++) {
            float4 a = a4[c4]; int cb = c4 * 4;
            acc += a.x * Wm[cb * 64 + d] + a.y * Wm[(cb + 1) * 64 + d]
                 + a.z * Wm[(cb + 2) * 64 + d] + a.w * Wm[(cb + 3) * 64 + d];
        }
        h2v[k] = acc;
    }
    float s2 = h2v[0];
    float w0 = Wpr2[en * 64 + d], w1 = Wpr2[640 + en * 64 + d], w2 = Wpr2[1280 + en * 64 + d];
    float gv2 = w0 + w1 * s2 + w2 * s2 * s2;
    st[grp][0 * 64 + d] = h2v[1] * gv2;
    st[grp][1 * 64 + d] = h2v[2] * gv2;
    st[grp][2 * 64 + d] = h2v[3] * gv2;
    __syncthreads();

    const float* Ws = Wsc2 + en * 4096;
    #pragma unroll
    for (int m = 0; m < 3; m++) {
        const float4* t4 = (const float4*)&st[grp][m * 64];
        const float4* o4 = (const float4*)&so1[grp][m * 64];
        float acc = 0.0f, sc = 0.0f;
        for (int c4 = 0; c4 < 16; c4++) {
            float4 t = t4[c4]; float4 o = o4[c4]; int cb = c4 * 4;
            acc += t.x * Wp2[cb * 64 + d] + t.y * Wp2[(cb + 1) * 64 + d]
                 + t.z * Wp2[(cb + 2) * 64 + d] + t.w * Wp2[(cb + 3) * 64 + d];
            sc  += o.x * Ws[cb * 64 + d] + o.y * Ws[(cb + 1) * 64 + d]
                 + o.z * Ws[(cb + 2) * 64 + d] + o.w * Ws[(cb + 3) * 64 + d];
        }
        so2[grp][m * 64 + d] = acc + sc;
    }
    __syncthreads();

    if (d < 48) {
        int m = d >> 4, h = d & 15;
        const float4* o4 = (const float4*)&so2[grp][m * 64];
        float acc = 0.0f;
        for (int c4 = 0; c4 < 16; c4++) {
            float4 o = o4[c4]; int cb = c4 * 4;
            acc += o.x * Wv[cb * 16 + h] + o.y * Wv[(cb + 1) * 16 + h]
                 + o.z * Wv[(cb + 2) * 16 + h] + o.w * Wv[(cb + 3) * 16 + h];
        }
        svh[grp][d] = acc;
    }
    __syncthreads();
    if (d < 16) {
        float v0 = svh[grp][d], v1 = svh[grp][16 + d], v2 = svh[grp][32 + d];
        sv[grp][d] = sqrtf(v0 * v0 + v1 * v1 + v2 * v2 + 1e-12f);
    }
    __syncthreads();
    if (d < 16) {
        float acc = bg1[d];
        for (int h = 0; h < 16; h++) acc += sv[grp][h] * Wg1[h * 16 + d];
        s_silu[grp][d] = silu_f(acc);
    }
    __syncthreads();
    if (d < 16) {
        float acc = bg2[d];
        for (int h = 0; h < 16; h++) acc += s_silu[grp][h] * Wg2[h * 16 + d];
        s_aw[grp][d] = acc * wrd2[d];
    }
    __syncthreads();
    if (d < 3) {
        float acc = 0.0f;
        for (int h = 0; h < 16; h++) acc += svh[grp][d * 16 + h] * s_aw[grp][h];
        float dv = d1[n * 3 + d] + acc;
        dip[n * 3 + d] = dv;
        atomicAdd(&total[batch[n] * 3 + d], dv + chg[n] * pos[n * 3 + d]);
    }
}

extern "C" void kernel_launch(void* const* d_in, const int* in_sizes, int n_in,
                              void* d_out, int out_size, void* d_ws, size_t ws_size,
                              hipStream_t stream) {
    const float* na     = (const float*)d_in[0];
    const float* pos    = (const float*)d_in[1];
    const float* shifts = (const float*)d_in[2];
    const float* chg    = (const float*)d_in[3];
    const int*   eidx   = (const int*)d_in[4];
    const int*   batch  = (const int*)d_in[5];
    const float* Wemb   = (const float*)d_in[7];
    const float* Wr1a   = (const float*)d_in[8];
    const float* Wr1b   = (const float*)d_in[9];
    const float* Wmix1  = (const float*)d_in[10];
    const float* Wsc1   = (const float*)d_in[11];
    const float* Wp1s   = (const float*)d_in[12];
    const float* Wp1v   = (const float*)d_in[13];
    const float* Wp10   = (const float*)d_in[14];
    const float* Wp11   = (const float*)d_in[15];
    const float* wrd1   = (const float*)d_in[16];
    const float* Wr2a   = (const float*)d_in[17];
    const float* Wr2b   = (const float*)d_in[18];
    const float* Wmix2  = (const float*)d_in[19];
    const float* Wsc2   = (const float*)d_in[20];
    const float* Wpr2   = (const float*)d_in[21];
    const float* Wp2    = (const float*)d_in[22];
    const float* Wv     = (const float*)d_in[23];
    const float* Wg1    = (const float*)d_in[24];
    const float* bg1    = (const float*)d_in[25];
    const float* Wg2    = (const float*)d_in[26];
    const float* bg2    = (const float*)d_in[27];
    const float* wrd2   = (const float*)d_in[28];

    float* ws   = (float*)d_ws;
    float* h0   = ws;                        // N*C
    float* A    = h0 + (size_t)NN * CC;      // N*4*C
    float* out0 = A + (size_t)NN * 4 * CC;   // N*C
    float* out1 = out0 + (size_t)NN * CC;    // N*3*C
    float* d1   = out1 + (size_t)NN * 3 * CC;// N*3
    int*   elem = (int*)(d1 + (size_t)NN * 3);

    float* total = (float*)d_out;            // G*3
    float* dip   = total + GG * 3;           // N*3

    hipMemsetAsync(A, 0, (size_t)NN * 4 * CC * sizeof(float), stream);
    hipMemsetAsync(total, 0, (size_t)GG * 3 * sizeof(float), stream);

    k_h0<<<NN / 4, 256, 0, stream>>>(na, Wemb, h0, elem);
    edge_tile<<<EE / 64, 256, 0, stream>>>(h0, pos, shifts, eidx, Wr1a, Wr1b, A);
    node1<<<NN / 4, 256, 0, stream>>>(h0, elem, A, Wmix1, Wsc1, Wp1s, Wp1v, Wp10, Wp11, wrd1,
                                      out0, out1, d1);
    hipMemsetAsync(A, 0, (size_t)NN * 4 * CC * sizeof(float), stream);
    edge_tile<<<EE / 64, 256, 0, stream>>>(out0, pos, shifts, eidx, Wr2a, Wr2b, A);
    node2<<<NN / 4, 256, 0, stream>>>(elem, A, out1, d1, Wmix2, Wsc2, Wpr2, Wp2, Wv,
                                      Wg1, bg1, Wg2, bg2, wrd2, batch, chg, pos, total, dip);
}

// Round 3
// 377.433 us; speedup vs baseline: 3.6273x; 3.6273x over previous
//
#include <hip/hip_runtime.h>
#include <math.h>

#define NN 8192
#define EE 131072
#define CC 64
#define GG 32

__device__ __forceinline__ float silu_f(float x) { return x / (1.0f + __expf(-x)); }

// ---------------- h0 = node_attrs @ W_embed ; elem = argmax(node_attrs) -------------
__global__ __launch_bounds__(256) void k_h0(const float* __restrict__ na,
                                            const float* __restrict__ Wemb,
                                            float* __restrict__ h0,
                                            int* __restrict__ elem) {
    int n = blockIdx.x * 4 + (threadIdx.x >> 6);
    int d = threadIdx.x & 63;
    float acc = 0.0f;
    float best = -1.0f; int bi = 0;
    #pragma unroll
    for (int k = 0; k < 10; k++) {
        float a = na[n * 10 + k];
        acc += a * Wemb[k * 64 + d];
        if (a > best) { best = a; bi = k; }
    }
    h0[n * 64 + d] = acc;
    if (d == 0) elem[n] = bi;
}

// ---------------- tiled edge kernel: 64 edges per block ----------------------------
// Phases: A geometry+radial  B hidden layer  C 64x128 GEMM (reg tile)
//         T transpose via LDS (swizzled)     S coalesced wave-per-edge atomics
__global__ __launch_bounds__(256) void edge_tile(
    const float* __restrict__ feats,  // (N,C)
    const float* __restrict__ pos,    // (N,3)
    const float* __restrict__ shifts, // (E,3)
    const int*   __restrict__ eidx,   // (2,E)
    const float* __restrict__ Wra,    // (8,64)
    const float* __restrict__ Wrb,    // (64,256) cols 0..127 used
    float* __restrict__ A)            // (N,4,C)
{
    // smem layout (floats):
    //   [0,8704)    : sWaT(512) + sWbT(8192)   -- phases A..C
    //                 overlay: sMsg(8448)      -- phases T..S
    //   [8704,9216) : sRb(512)
    //   [9216,13568): sHidT 64*68 (4352)
    //   [13568,13760): sU (192)
    __shared__ float smem[13760];
    __shared__ int   sSnd[64], sRcv[64], sLive[64];
    float* sWaT  = smem;
    float* sWbT  = smem + 512;
    float* sMsg  = smem;
    float* sRb   = smem + 8704;
    float* sHidT = smem + 9216;
    float* sU    = smem + 13568;

    int tid = threadIdx.x;
    int e_base = blockIdx.x * 64;

    // ---- phase A: geometry + radial basis (wave 0) + weight staging (all) ---------
    if (tid < 64) {
        int e = e_base + tid;
        int snd = eidx[e];
        int rcv = eidx[EE + e];
        float vx = pos[rcv * 3 + 0] - pos[snd * 3 + 0] + shifts[e * 3 + 0];
        float vy = pos[rcv * 3 + 1] - pos[snd * 3 + 1] + shifts[e * 3 + 1];
        float vz = pos[rcv * 3 + 2] - pos[snd * 3 + 2] + shifts[e * 3 + 2];
        float r = sqrtf(vx * vx + vy * vy + vz * vz + 1e-12f);
        float rinv = 1.0f / r;
        float x = r * 0.2f;
        int live = x < 1.0f;
        float pref = 0.0f;
        if (live) {
            float x2 = x * x, x4 = x2 * x2, x5 = x4 * x;
            float env = 1.0f - 21.0f * x5 + 35.0f * x5 * x - 15.0f * x5 * x2;
            pref = 0.632455532033676f * rinv * env;   // sqrt(2/5)/r * env
        }
        float s1, c1;
        __sincosf(0.62831853071795865f * r, &s1, &c1);   // pi/5 * r
        float k2c = 2.0f * c1;
        float sp = 0.0f, sn = s1;
        #pragma unroll
        for (int b = 0; b < 8; b++) {
            sRb[b * 64 + tid] = pref * sn;
            float t = k2c * sn - sp; sp = sn; sn = t;
        }
        sU[tid]       = vx * rinv;
        sU[64 + tid]  = vy * rinv;
        sU[128 + tid] = vz * rinv;
        sSnd[tid] = snd; sRcv[tid] = rcv; sLive[tid] = live;
    }
    // stage Wa transposed: sWaT[j][b]
    for (int idx = tid; idx < 512; idx += 256) {
        int b = idx >> 6, j = idx & 63;
        sWaT[j * 8 + b] = Wra[idx];
    }
    // stage Wb transposed [c][j], j-block XOR swizzle, scales folded (1/16, sqrt3/16)
    for (int idx = tid; idx < 64 * 128; idx += 256) {
        int j = idx >> 7, c = idx & 127;
        float v = Wrb[j * 256 + c] * (c < 64 ? 0.0625f : 0.10825317547305482f);
        int jb = j >> 2, jl = j & 3;
        int sj = ((jb ^ ((c >> 3) & 7)) << 2) | jl;
        sWbT[c * 64 + sj] = v;
    }
    __syncthreads();

    // ---- phase B: hidden layer (all 256 threads) -----------------------------------
    {
        int e = tid & 63, jg = tid >> 6;
        float rbv[8];
        #pragma unroll
        for (int b = 0; b < 8; b++) rbv[b] = sRb[b * 64 + e];
        const float4* waT4 = (const float4*)sWaT;
        float hid[16];
        #pragma unroll
        for (int jj = 0; jj < 16; jj++) {
            int j = jg * 16 + jj;
            float4 wa0 = waT4[j * 2 + 0];
            float4 wa1 = waT4[j * 2 + 1];
            float acc = rbv[0] * wa0.x + rbv[1] * wa0.y + rbv[2] * wa0.z + rbv[3] * wa0.w
                      + rbv[4] * wa1.x + rbv[5] * wa1.y + rbv[6] * wa1.z + rbv[7] * wa1.w;
            hid[jj] = silu_f(acc);
        }
        float4* hidT4 = (float4*)sHidT;
        int hk = (e >> 1) & 7;
        #pragma unroll
        for (int q = 0; q < 4; q++) {
            int j4 = jg * 4 + q;
            hidT4[e * 17 + (j4 ^ hk)] =
                make_float4(hid[q * 4 + 0], hid[q * 4 + 1], hid[q * 4 + 2], hid[q * 4 + 3]);
        }
    }
    __syncthreads();

    // ---- phase C: wrf = hid @ WbT, register tile 4 edges x 8 cols -------------------
    int cg = tid & 15, eg = tid >> 4;
    int e0 = eg * 4, c0 = cg * 8, cgl = cg & 7;
    const float4* hidT4 = (const float4*)sHidT;  // row stride 17 float4
    const float4* wbT4  = (const float4*)sWbT;   // row stride 16 float4
    int hk0 = ((e0 + 0) >> 1) & 7, hk1 = ((e0 + 1) >> 1) & 7;
    int hk2 = ((e0 + 2) >> 1) & 7, hk3 = ((e0 + 3) >> 1) & 7;
    float acc[4][8];
    #pragma unroll
    for (int i = 0; i < 4; i++)
        #pragma unroll
        for (int cc = 0; cc < 8; cc++) acc[i][cc] = 0.0f;

    for (int jb = 0; jb < 16; ++jb) {
        float4 h0_ = hidT4[(e0 + 0) * 17 + (jb ^ hk0)];
        float4 h1_ = hidT4[(e0 + 1) * 17 + (jb ^ hk1)];
        float4 h2_ = hidT4[(e0 + 2) * 17 + (jb ^ hk2)];
        float4 h3_ = hidT4[(e0 + 3) * 17 + (jb ^ hk3)];
        int wj = jb ^ cgl;
        #pragma unroll
        for (int cc = 0; cc < 8; cc++) {
            float4 wb = wbT4[(c0 + cc) * 16 + wj];
            acc[0][cc] += h0_.x * wb.x + h0_.y * wb.y + h0_.z * wb.z + h0_.w * wb.w;
            acc[1][cc] += h1_.x * wb.x + h1_.y * wb.y + h1_.z * wb.z + h1_.w * wb.w;
            acc[2][cc] += h2_.x * wb.x + h2_.y * wb.y + h2_.z * wb.z + h2_.w * wb.w;
            acc[3][cc] += h3_.x * wb.x + h3_.y * wb.y + h3_.z * wb.z + h3_.w * wb.w;
        }
    }
    __syncthreads();   // all reads of sWbT done before sMsg overlay write

    // ---- phase T: transpose results into sMsg (row stride 132, XOR-swizzled) -------
    {
        float4* msg4 = (float4*)sMsg;
        #pragma unroll
        for (int i = 0; i < 4; ++i) {
            int e = e0 + i, xk = e & 7;
            msg4[e * 33 + ((2 * cg + 0) ^ xk)] =
                make_float4(acc[i][0], acc[i][1], acc[i][2], acc[i][3]);
            msg4[e * 33 + ((2 * cg + 1) ^ xk)] =
                make_float4(acc[i][4], acc[i][5], acc[i][6], acc[i][7]);
        }
    }
    __syncthreads();

    // ---- phase S: coalesced wave-per-edge atomic scatter ----------------------------
    {
        int q = tid >> 6, c = tid & 63;
        #pragma unroll 4
        for (int i = 0; i < 16; ++i) {
            int e = q * 16 + i;
            if (!sLive[e]) continue;
            int snd = sSnd[e], rcv = sRcv[e];
            float f = feats[(size_t)snd * CC + c];
            float ux = sU[e], uy = sU[64 + e], uz = sU[128 + e];
            int xk = e & 7;
            float w0 = sMsg[e * 132 + (((c >> 2) ^ xk) << 2) + (c & 3)];
            float w1 = sMsg[e * 132 + (((16 + (c >> 2)) ^ xk) << 2) + (c & 3)];
            float m0 = w0 * f, g = w1 * f;
            float* Ar = A + (size_t)rcv * 256;
            atomicAdd(Ar + c,        m0);
            atomicAdd(Ar + 64 + c,   g * ux);
            atomicAdd(Ar + 128 + c,  g * uy);
            atomicAdd(Ar + 192 + c,  g * uz);
        }
    }
}

// ---------------- node update 1 (4 nodes per block) --------------------------------
__global__ __launch_bounds__(256) void node1(
    const float* __restrict__ h0, const int* __restrict__ elem,
    const float* __restrict__ A,
    const float* __restrict__ Wmix1, const float* __restrict__ Wsc1,
    const float* __restrict__ Wp1s, const float* __restrict__ Wp1v,
    const float* __restrict__ Wp10, const float* __restrict__ Wp11,
    const float* __restrict__ wrd1,
    float* __restrict__ out0, float* __restrict__ out1, float* __restrict__ d1)
{
    int grp = threadIdx.x >> 6, d = threadIdx.x & 63;
    int n = blockIdx.x * 4 + grp;
    __shared__ float sA[4][256];
    __shared__ float sh0[4][64];
    __shared__ float sm0[4][64];
    __shared__ float st[4][3 * 64];

    #pragma unroll
    for (int k = 0; k < 4; k++) sA[grp][k * 64 + d] = A[(size_t)n * 256 + k * 64 + d];
    sh0[grp][d] = h0[n * 64 + d];
    __syncthreads();

    int en = elem[n];
    float h1v[4];
    #pragma unroll
    for (int k = 0; k < 4; k++) {
        const float* Wm = Wmix1 + (k ? 4096 : 0);
        const float4* a4 = (const float4*)&sA[grp][k * 64];
        float acc = 0.0f;
        for (int c4 = 0; c4 < 16; c4++) {
            float4 a = a4[c4]; int cb = c4 * 4;
            acc += a.x * Wm[cb * 64 + d] + a.y * Wm[(cb + 1) * 64 + d]
                 + a.z * Wm[(cb + 2) * 64 + d] + a.w * Wm[(cb + 3) * 64 + d];
        }
        h1v[k] = acc;
    }
    const float* Ws = Wsc1 + en * 4096;
    float sc = 0.0f;
    {
        const float4* a4 = (const float4*)&sh0[grp][0];
        for (int c4 = 0; c4 < 16; c4++) {
            float4 a = a4[c4]; int cb = c4 * 4;
            sc += a.x * Ws[cb * 64 + d] + a.y * Ws[(cb + 1) * 64 + d]
                + a.z * Ws[(cb + 2) * 64 + d] + a.w * Ws[(cb + 3) * 64 + d];
        }
    }

    float s = h1v[0];
    float ws0 = Wp1s[en * 64 + d], ws1 = Wp1s[640 + en * 64 + d], ws2 = Wp1s[1280 + en * 64 + d];
    float wv0 = Wp1v[en * 64 + d], wv1 = Wp1v[640 + en * 64 + d], wv2 = Wp1v[1280 + en * 64 + d];
    float m0 = ws0 * s + ws1 * s * s + ws2 * s * s * s;
    float gv = wv0 + wv1 * s + wv2 * s * s;
    sm0[grp][d] = m0;
    st[grp][0 * 64 + d] = h1v[1] * gv;
    st[grp][1 * 64 + d] = h1v[2] * gv;
    st[grp][2 * 64 + d] = h1v[3] * gv;
    __syncthreads();

    float o0 = sc;
    {
        const float4* a4 = (const float4*)&sm0[grp][0];
        for (int c4 = 0; c4 < 16; c4++) {
            float4 a = a4[c4]; int cb = c4 * 4;
            o0 += a.x * Wp10[cb * 64 + d] + a.y * Wp10[(cb + 1) * 64 + d]
                + a.z * Wp10[(cb + 2) * 64 + d] + a.w * Wp10[(cb + 3) * 64 + d];
        }
    }
    out0[n * 64 + d] = o0;

    float wr = wrd1[d];
    #pragma unroll
    for (int m = 0; m < 3; m++) {
        const float4* a4 = (const float4*)&st[grp][m * 64];
        float acc = 0.0f;
        for (int c4 = 0; c4 < 16; c4++) {
            float4 a = a4[c4]; int cb = c4 * 4;
            acc += a.x * Wp11[cb * 64 + d] + a.y * Wp11[(cb + 1) * 64 + d]
                 + a.z * Wp11[(cb + 2) * 64 + d] + a.w * Wp11[(cb + 3) * 64 + d];
        }
        out1[((size_t)n * 3 + m) * 64 + d] = acc;
        float v = acc * wr;
        #pragma unroll
        for (int off = 32; off > 0; off >>= 1) v += __shfl_down(v, off);
        if (d == 0) d1[n * 3 + m] = v;
    }
}

// ---------------- node update 2 + readout (4 nodes per block) ----------------------
__global__ __launch_bounds__(256) void node2(
    const int* __restrict__ elem, const float* __restrict__ A,
    const float* __restrict__ out1, const float* __restrict__ d1,
    const float* __restrict__ Wmix2, const float* __restrict__ Wsc2,
    const float* __restrict__ Wpr2, const float* __restrict__ Wp2,
    const float* __restrict__ Wv, const float* __restrict__ Wg1,
    const float* __restrict__ bg1, const float* __restrict__ Wg2,
    const float* __restrict__ bg2, const float* __restrict__ wrd2,
    const int* __restrict__ batch, const float* __restrict__ chg,
    const float* __restrict__ pos,
    float* __restrict__ total, float* __restrict__ dip)
{
    int grp = threadIdx.x >> 6, d = threadIdx.x & 63;
    int n = blockIdx.x * 4 + grp;
    __shared__ float sA[4][256];
    __shared__ float so1[4][3 * 64];
    __shared__ float st[4][3 * 64];
    __shared__ float so2[4][3 * 64];
    __shared__ float svh[4][48];
    __shared__ float sv[4][16];
    __shared__ float s_silu[4][16];
    __shared__ float s_aw[4][16];

    #pragma unroll
    for (int k = 0; k < 4; k++) sA[grp][k * 64 + d] = A[(size_t)n * 256 + k * 64 + d];
    #pragma unroll
    for (int m = 0; m < 3; m++) so1[grp][m * 64 + d] = out1[((size_t)n * 3 + m) * 64 + d];
    __syncthreads();

    int en = elem[n];
    float h2v[4];
    #pragma unroll
    for (int k = 0; k < 4; k++) {
        const float* Wm = Wmix2 + (k ? 4096 : 0);
        const float4* a4 = (const float4*)&sA[grp][k * 64];
        float acc = 0.0f;
        for (int c4 = 0; c4 < 16; c4++) {
            float4 a = a4[c4]; int cb = c4 * 4;
            acc += a.x * Wm[cb * 64 + d] + a.y * Wm[(cb + 1) * 64 + d]
                 + a.z * Wm[(cb + 2) * 64 + d] + a.w * Wm[(cb + 3) * 64 + d];
        }
        h2v[k] = acc;
    }
    float s2 = h2v[0];
    float w0 = Wpr2[en * 64 + d], w1 = Wpr2[640 + en * 64 + d], w2 = Wpr2[1280 + en * 64 + d];
    float gv2 = w0 + w1 * s2 + w2 * s2 * s2;
    st[grp][0 * 64 + d] = h2v[1] * gv2;
    st[grp][1 * 64 + d] = h2v[2] * gv2;
    st[grp][2 * 64 + d] = h2v[3] * gv2;
    __syncthreads();

    const float* Ws = Wsc2 + en * 4096;
    #pragma unroll
    for (int m = 0; m < 3; m++) {
        const float4* t4 = (const float4*)&st[grp][m * 64];
        const float4* o4 = (const float4*)&so1[grp][m * 64];
        float acc = 0.0f, sc = 0.0f;
        for (int c4 = 0; c4 < 16; c4++) {
            float4 t = t4[c4]; float4 o = o4[c4]; int cb = c4 * 4;
            acc += t.x * Wp2[cb * 64 + d] + t.y * Wp2[(cb + 1) * 64 + d]
                 + t.z * Wp2[(cb + 2) * 64 + d] + t.w * Wp2[(cb + 3) * 64 + d];
            sc  += o.x * Ws[cb * 64 + d] + o.y * Ws[(cb + 1) * 64 + d]
                 + o.z * Ws[(cb + 2) * 64 + d] + o.w * Ws[(cb + 3) * 64 + d];
        }
        so2[grp][m * 64 + d] = acc + sc;
    }
    __syncthreads();

    if (d < 48) {
        int m = d >> 4, h = d & 15;
        const float4* o4 = (const float4*)&so2[grp][m * 64];
        float acc = 0.0f;
        for (int c4 = 0; c4 < 16; c4++) {
            float4 o = o4[c4]; int cb = c4 * 4;
            acc += o.x * Wv[cb * 16 + h] + o.y * Wv[(cb + 1) * 16 + h]
                 + o.z * Wv[(cb + 2) * 16 + h] + o.w * Wv[(cb + 3) * 16 + h];
        }
        svh[grp][d] = acc;
    }
    __syncthreads();
    if (d < 16) {
        float v0 = svh[grp][d], v1 = svh[grp][16 + d], v2 = svh[grp][32 + d];
        sv[grp][d] = sqrtf(v0 * v0 + v1 * v1 + v2 * v2 + 1e-12f);
    }
    __syncthreads();
    if (d < 16) {
        float acc = bg1[d];
        for (int h = 0; h < 16; h++) acc += sv[grp][h] * Wg1[h * 16 + d];
        s_silu[grp][d] = silu_f(acc);
    }
    __syncthreads();
    if (d < 16) {
        float acc = bg2[d];
        for (int h = 0; h < 16; h++) acc += s_silu[grp][h] * Wg2[h * 16 + d];
        s_aw[grp][d] = acc * wrd2[d];
    }
    __syncthreads();
    if (d < 3) {
        float acc = 0.0f;
        for (int h = 0; h < 16; h++) acc += svh[grp][d * 16 + h] * s_aw[grp][h];
        float dv = d1[n * 3 + d] + acc;
        dip[n * 3 + d] = dv;
        atomicAdd(&total[batch[n] * 3 + d], dv + chg[n] * pos[n * 3 + d]);
    }
}

extern "C" void kernel_launch(void* const* d_in, const int* in_sizes, int n_in,
                              void* d_out, int out_size, void* d_ws, size_t ws_size,
                              hipStream_t stream) {
    const float* na     = (const float*)d_in[0];
    const float* pos    = (const float*)d_in[1];
    const float* shifts = (const float*)d_in[2];
    const float* chg    = (const float*)d_in[3];
    const int*   eidx   = (const int*)d_in[4];
    const int*   batch  = (const int*)d_in[5];
    const float* Wemb   = (const float*)d_in[7];
    const float* Wr1a   = (const float*)d_in[8];
    const float* Wr1b   = (const float*)d_in[9];
    const float* Wmix1  = (const float*)d_in[10];
    const float* Wsc1   = (const float*)d_in[11];
    const float* Wp1s   = (const float*)d_in[12];
    const float* Wp1v   = (const float*)d_in[13];
    const float* Wp10   = (const float*)d_in[14];
    const float* Wp11   = (const float*)d_in[15];
    const float* wrd1   = (const float*)d_in[16];
    const float* Wr2a   = (const float*)d_in[17];
    const float* Wr2b   = (const float*)d_in[18];
    const float* Wmix2  = (const float*)d_in[19];
    const float* Wsc2   = (const float*)d_in[20];
    const float* Wpr2   = (const float*)d_in[21];
    const float* Wp2    = (const float*)d_in[22];
    const float* Wv     = (const float*)d_in[23];
    const float* Wg1    = (const float*)d_in[24];
    const float* bg1    = (const float*)d_in[25];
    const float* Wg2    = (const float*)d_in[26];
    const float* bg2    = (const float*)d_in[27];
    const float* wrd2   = (const float*)d_in[28];

    float* ws   = (float*)d_ws;
    float* h0   = ws;                        // N*C
    float* A    = h0 + (size_t)NN * CC;      // N*4*C
    float* out0 = A + (size_t)NN * 4 * CC;   // N*C
    float* out1 = out0 + (size_t)NN * CC;    // N*3*C
    float* d1   = out1 + (size_t)NN * 3 * CC;// N*3
    int*   elem = (int*)(d1 + (size_t)NN * 3);

    float* total = (float*)d_out;            // G*3
    float* dip   = total + GG * 3;           // N*3

    hipMemsetAsync(A, 0, (size_t)NN * 4 * CC * sizeof(float), stream);
    hipMemsetAsync(total, 0, (size_t)GG * 3 * sizeof(float), stream);

    k_h0<<<NN / 4, 256, 0, stream>>>(na, Wemb, h0, elem);
    edge_tile<<<EE / 64, 256, 0, stream>>>(h0, pos, shifts, eidx, Wr1a, Wr1b, A);
    node1<<<NN / 4, 256, 0, stream>>>(h0, elem, A, Wmix1, Wsc1, Wp1s, Wp1v, Wp10, Wp11, wrd1,
                                      out0, out1, d1);
    hipMemsetAsync(A, 0, (size_t)NN * 4 * CC * sizeof(float), stream);
    edge_tile<<<EE / 64, 256, 0, stream>>>(out0, pos, shifts, eidx, Wr2a, Wr2b, A);
    node2<<<NN / 4, 256, 0, stream>>>(elem, A, out1, d1, Wmix2, Wsc2, Wpr2, Wp2, Wv,
                                      Wg1, bg1, Wg2, bg2, wrd2, batch, chg, pos, total, dip);
}